// Round 10
// baseline (234.435 us; speedup 1.0000x reference)
//
#include <hip/hip_runtime.h>
#include <math.h>

#define M_TOTAL 35642          // bs * nq
#define NQ_ 17821
#define NV_ 17821
#define EMB 256
#define KDIM 256
#define QB 8
#define BM 64
#define BN 64
#define NTILES 10              // 640 / 64
#define MTILES ((M_TOTAL + BM - 1) / BM)   // 557

// ---- workspace layout (bytes) ----
#define WS_VAL_OFF   0ull
#define WS_VAL_BYTES (2ull * M_TOTAL * EMB)        // f16 value, head-major [2][8][NV_][32]
#define WS_OFFW_OFF  (WS_VAL_OFF + WS_VAL_BYTES)
#define WS_OFFW_BYTES (2ull * M_TOTAL * EMB)       // f16 off  [m][256]
#define WS_ATT_OFF   (WS_OFFW_OFF + WS_OFFW_BYTES)
#define WS_ATT_BYTES (2ull * M_TOTAL * 128)        // f16 attn logits [m][128]
#define WS_SAMP_OFF  (WS_ATT_OFF + WS_ATT_BYTES)   // 45,621,760
#define WS_SAMP_BYTES (2ull * M_TOTAL * EMB)       // f16 samp [m][256]
#define WS_NEED2     (WS_SAMP_OFF + WS_SAMP_BYTES) // 63,870,464 B (proven fits, r9)
// WH (f16 [640][256], 327,680 B) OVERLAYS the samp region: WH is read only by
// k_gemm1, samp is written only by k_gather (after gemm1) -> disjoint lifetimes.
#define WS_WH_OFF    WS_SAMP_OFF

using f16x8 = __attribute__((ext_vector_type(8))) _Float16;
using f32x4 = __attribute__((ext_vector_type(4))) float;
typedef _Float16 half2v __attribute__((ext_vector_type(2)));

__device__ __forceinline__ unsigned short f2h(float f) {
  union { _Float16 h; unsigned short u; } v; v.h = (_Float16)f; return v.u;
}

#if defined(__has_builtin)
#if __has_builtin(__builtin_amdgcn_fdot2) && __has_builtin(__builtin_amdgcn_perm)
#define USE_DOT2 1
#endif
#endif

// acc2: s0 += v00.ch0*w.x + v01.ch0*w.y ; s1 += (ch1 ...) for a packed-f16
// corner pair. a = uint holding 2 f16 channels of corner A, b = corner B.
__device__ __forceinline__ void acc2(float& s0, float& s1, unsigned a, unsigned b, half2v w) {
#ifdef USE_DOT2
  const unsigned pl = __builtin_amdgcn_perm(b, a, 0x05040100u);  // (a.lo, b.lo)
  const unsigned ph = __builtin_amdgcn_perm(b, a, 0x07060302u);  // (a.hi, b.hi)
  union { unsigned u; half2v h; } cl, ch;
  cl.u = pl; ch.u = ph;
  s0 = __builtin_amdgcn_fdot2(cl.h, w, s0, false);
  s1 = __builtin_amdgcn_fdot2(ch.h, w, s1, false);
#else
  union { unsigned u; half2v h; } ua, ub;
  ua.u = a; ub.u = b;
  s0 += (float)ua.h[0] * (float)w[0] + (float)ub.h[0] * (float)w[1];
  s1 += (float)ua.h[1] * (float)w[0] + (float)ub.h[1] * (float)w[1];
#endif
}

// ---- k_prep: weights f32 -> f16 [640][256] (Wv rows 0-255, Woff 256-511, Wattn 512-639) ----
__global__ __launch_bounds__(256) void k_prep(
    const float* __restrict__ Wv, const float* __restrict__ Woff,
    const float* __restrict__ Wattn, _Float16* __restrict__ WH) {
  const int i = blockIdx.x * 256 + threadIdx.x;   // 8 elems each
  if (i >= 640 * 256 / 8) return;
  const int e   = i * 8;
  const int row = e >> 8;
  const int col = e & 255;
  const float* src = (row < 256) ? (Wv + (size_t)row * 256)
                   : (row < 512) ? (Woff + (size_t)(row - 256) * 256)
                                 : (Wattn + (size_t)(row - 512) * 256);
  const float4 a = *reinterpret_cast<const float4*>(src + col);
  const float4 b = *reinterpret_cast<const float4*>(src + col + 4);
  union { _Float16 h[8]; uint4 u; } p;
  p.h[0] = (_Float16)a.x; p.h[1] = (_Float16)a.y; p.h[2] = (_Float16)a.z; p.h[3] = (_Float16)a.w;
  p.h[4] = (_Float16)b.x; p.h[5] = (_Float16)b.y; p.h[6] = (_Float16)b.z; p.h[7] = (_Float16)b.w;
  *reinterpret_cast<uint4*>(WH + e) = p.u;
}

// ---- k_gemm1: one M-tile per block, loops all 10 N-tiles; A staged once ----
__global__ __launch_bounds__(256) void k_gemm1(
    const float* __restrict__ Q,
    const _Float16* __restrict__ WH,
    const float* __restrict__ bv, const float* __restrict__ boff,
    const float* __restrict__ battn,
    unsigned short* __restrict__ valH,
    unsigned short* __restrict__ offH,
    unsigned short* __restrict__ attH) {

  __shared__ _Float16 Sh[BM * 256];   // 32 KB, A then reused for each B tile

  const int t = threadIdx.x;
  const int lane = t & 63;
  const int wid = t >> 6;
  const int wr = wid >> 1, wc = wid & 1;
  const int mb = blockIdx.x * BM;

  // ---- stage A (Q rows, f32->f16, 16B-chunk XOR swizzle) ----
#pragma unroll
  for (int i = 0; i < 16; ++i) {
    const int g    = i * 256 + t;        // 0..4095 float4 slots
    const int row  = g >> 6;             // 64 float4 per row
    const int c4   = g & 63;
    const int c8   = c4 >> 1;            // 8-f16 chunk 0..31
    const int half = c4 & 1;
    const int eo   = row * 256 + ((c8 ^ (row & 7)) * 8) + half * 4;
    int ar = mb + row; if (ar > M_TOTAL - 1) ar = M_TOTAL - 1;
    const float4 qa = *reinterpret_cast<const float4*>(Q + (size_t)ar * KDIM + c4 * 4);
    union { _Float16 h[4]; uint2 u; } p;
    p.h[0] = (_Float16)qa.x; p.h[1] = (_Float16)qa.y;
    p.h[2] = (_Float16)qa.z; p.h[3] = (_Float16)qa.w;
    *reinterpret_cast<uint2*>(&Sh[eo]) = p.u;
  }
  __syncthreads();

  // ---- A-frags (full K) to registers: 16 x f16x8 = 64 VGPR ----
  f16x8 af[8][2];
#pragma unroll
  for (int kk = 0; kk < 8; ++kk)
#pragma unroll
    for (int f = 0; f < 2; ++f) {
      const int arow = wr * 32 + f * 16 + (lane & 15);
      const int ac   = (kk * 4 + (lane >> 4)) ^ (arow & 7);
      af[kk][f] = *reinterpret_cast<f16x8*>(&Sh[arow * 256 + ac * 8]);
    }
  __syncthreads();   // frag reads complete before B overwrites Sh

  for (int nt = 0; nt < NTILES; ++nt) {
    const int nb = nt * BN;
    // ---- stage B tile (f16 source, no cvt), swizzled ----
#pragma unroll
    for (int i = 0; i < 8; ++i) {
      const int g   = i * 256 + t;       // 0..2047 uint4 slots
      const int row = g >> 5;            // 32 chunks per row
      const int c8  = g & 31;
      const int eo  = row * 256 + ((c8 ^ (row & 7)) * 8);
      *reinterpret_cast<uint4*>(&Sh[eo]) =
          *reinterpret_cast<const uint4*>(WH + (size_t)(nb + row) * 256 + c8 * 8);
    }
    __syncthreads();

    f32x4 acc[2][2];
#pragma unroll
    for (int a = 0; a < 2; ++a)
#pragma unroll
      for (int b = 0; b < 2; ++b) acc[a][b] = (f32x4)0.f;

#pragma unroll
    for (int kk = 0; kk < 8; ++kk) {
      f16x8 bf[2];
#pragma unroll
      for (int f = 0; f < 2; ++f) {
        const int brow = wc * 32 + f * 16 + (lane & 15);
        const int bc   = (kk * 4 + (lane >> 4)) ^ (brow & 7);
        bf[f] = *reinterpret_cast<f16x8*>(&Sh[brow * 256 + bc * 8]);
      }
#pragma unroll
      for (int fr = 0; fr < 2; ++fr)
#pragma unroll
        for (int fc = 0; fc < 2; ++fc)
          acc[fr][fc] = __builtin_amdgcn_mfma_f32_16x16x32_f16(af[kk][fr], bf[fc], acc[fr][fc], 0, 0, 0);
    }
    __syncthreads();   // Sh free for next nt

    // ---- epilogue for this nt ----
    {
      const float* bsec; int nsb;
      if (nt < 4)      { bsec = bv;    nsb = 0;   }
      else if (nt < 8) { bsec = boff;  nsb = 256; }
      else             { bsec = battn; nsb = 512; }
      const int nrow0 = nb - nsb;
      const int col = lane & 15;
      const int rg4 = lane >> 4;
      float bias2[2];
      bias2[0] = bsec[nrow0 + wc * 32 + 0 * 16 + col];
      bias2[1] = bsec[nrow0 + wc * 32 + 1 * 16 + col];
#pragma unroll
      for (int fr = 0; fr < 2; ++fr) {
#pragma unroll
        for (int fc = 0; fc < 2; ++fc) {
          const int n = nb + wc * 32 + fc * 16 + col;
#pragma unroll
          for (int j = 0; j < 4; ++j) {
            const int m = mb + wr * 32 + fr * 16 + rg4 * 4 + j;
            if (m < M_TOTAL) {
              const unsigned short o = f2h(acc[fr][fc][j] + bias2[fc]);
              if (nsb == 0) {
                const int b  = (m >= NQ_) ? 1 : 0;
                const int mm = m - b * NQ_;
                valH[((size_t)(b * 8 + (n >> 5)) * NV_ + mm) * 32 + (n & 31)] = o;
              } else if (nsb == 256) {
                offH[(size_t)m * 256 + (n - 256)] = o;
              } else {
                attH[(size_t)m * 128 + (n - 512)] = o;
              }
            }
          }
        }
      }
    }
  }
}

// ---- k_gather: softmax + bilinear gather (f16, dot2) -> f16 samp ws ----
__global__ __launch_bounds__(256) void k_gather(
    const float* __restrict__ refp,
    const unsigned short* __restrict__ valH,
    const unsigned short* __restrict__ offH,
    const unsigned short* __restrict__ attH,
    unsigned short* __restrict__ sampH) {

  const int t  = threadIdx.x;
  const int q0 = blockIdx.x * QB;
  const int q  = t >> 5;
  const int h  = (t >> 2) & 7;
  const int dq = t & 3;
  const int m  = q0 + q;
  const int mc = min(m, M_TOTAL - 1);

  // softmax over f16 logits
  float aw[16];
  {
    const f16x8 a0 = *reinterpret_cast<const f16x8*>(attH + (size_t)mc * 128 + h * 16);
    const f16x8 a1 = *reinterpret_cast<const f16x8*>(attH + (size_t)mc * 128 + h * 16 + 8);
#pragma unroll
    for (int i = 0; i < 8; ++i) { aw[i] = (float)a0[i]; aw[8 + i] = (float)a1[i]; }
  }
  float mx = aw[0];
#pragma unroll
  for (int i = 1; i < 16; ++i) mx = fmaxf(mx, aw[i]);
  float ssum = 0.f;
#pragma unroll
  for (int i = 0; i < 16; ++i) { aw[i] = __expf(aw[i] - mx); ssum += aw[i]; }
  const float inv = 1.0f / ssum;
#pragma unroll
  for (int i = 0; i < 16; ++i) aw[i] *= inv;

  float sacc[8];
#pragma unroll
  for (int d = 0; d < 8; ++d) sacc[d] = 0.f;

  {
    constexpr int LH[4] = {100, 50, 25, 13};
    constexpr int LW[4] = {134, 67, 34, 17};
    constexpr int LS[4] = {0, 13400, 16750, 17600};
    const int b = (mc >= NQ_) ? 1 : 0;
    const float* rp = refp + (size_t)mc * 8;
    const uint4* vb = reinterpret_cast<const uint4*>(valH) + (size_t)(b * 8 + h) * NV_ * 4 + dq;

#pragma unroll
    for (int lvl = 0; lvl < 4; ++lvl) {
      const int Hl = LH[lvl], Wl = LW[lvl], st = LS[lvl];
      const float Hf = (float)Hl, Wf = (float)Wl;
      const float2 rxy = *reinterpret_cast<const float2*>(rp + lvl * 2);
      const f16x8 ov = *reinterpret_cast<const f16x8*>(offH + (size_t)mc * 256 + h * 32 + lvl * 8);
#pragma unroll
      for (int p = 0; p < 4; ++p) {
        const float ox = (float)ov[p * 2 + 0];
        const float oy = (float)ov[p * 2 + 1];
        // (rx + ox/W)*W - 0.5 == rx*W + ox - 0.5 up to ~1 ulp (tolerance-safe)
        const float x = fmaf(rxy.x, Wf, ox) - 0.5f;
        const float y = fmaf(rxy.y, Hf, oy) - 0.5f;
        const float xf = floorf(x), yf = floorf(y);
        const float wx = x - xf, wy = y - yf;
        const int x0i = (int)xf, y0i = (int)yf;
        const int x1i = x0i + 1, y1i = y0i + 1;
        const float vx0 = (x0i >= 0 && x0i < Wl) ? 1.f : 0.f;
        const float vx1 = (x1i >= 0 && x1i < Wl) ? 1.f : 0.f;
        const float vy0 = (y0i >= 0 && y0i < Hl) ? 1.f : 0.f;
        const float vy1 = (y1i >= 0 && y1i < Hl) ? 1.f : 0.f;
        const int x0c = min(max(x0i, 0), Wl - 1);
        const int x1c = min(max(x1i, 0), Wl - 1);
        const int y0c = min(max(y0i, 0), Hl - 1);
        const int y1c = min(max(y1i, 0), Hl - 1);
        const float a = aw[lvl * 4 + p];
        const float w00 = a * (1.f - wy) * (1.f - wx) * (vy0 * vx0);
        const float w01 = a * (1.f - wy) * wx         * (vy0 * vx1);
        const float w10 = a * wy         * (1.f - wx) * (vy1 * vx0);
        const float w11 = a * wy         * wx         * (vy1 * vx1);
        const half2v wA = {(_Float16)w00, (_Float16)w01};
        const half2v wB = {(_Float16)w10, (_Float16)w11};
        const uint4 u00 = vb[(size_t)(st + y0c * Wl + x0c) * 4];
        const uint4 u01 = vb[(size_t)(st + y0c * Wl + x1c) * 4];
        const uint4 u10 = vb[(size_t)(st + y1c * Wl + x0c) * 4];
        const uint4 u11 = vb[(size_t)(st + y1c * Wl + x1c) * 4];
        acc2(sacc[0], sacc[1], u00.x, u01.x, wA);
        acc2(sacc[0], sacc[1], u10.x, u11.x, wB);
        acc2(sacc[2], sacc[3], u00.y, u01.y, wA);
        acc2(sacc[2], sacc[3], u10.y, u11.y, wB);
        acc2(sacc[4], sacc[5], u00.z, u01.z, wA);
        acc2(sacc[4], sacc[5], u10.z, u11.z, wB);
        acc2(sacc[6], sacc[7], u00.w, u01.w, wA);
        acc2(sacc[6], sacc[7], u10.w, u11.w, wB);
      }
    }
  }

  if (m < M_TOTAL) {
    union { _Float16 h[8]; uint4 u; } pk;
#pragma unroll
    for (int d = 0; d < 8; ++d) pk.h[d] = (_Float16)sacc[d];
    *reinterpret_cast<uint4*>(sampH + (size_t)m * 256 + h * 32 + dq * 8) = pk.u;
  }
}

// ---- k_gemm2: out = samp @ Wout^T + bout + Q (residual), MFMA (unchanged r9) ----
__global__ __launch_bounds__(256) void k_gemm2(
    const float* __restrict__ Q,
    const unsigned short* __restrict__ sampH,   // f16 bits [m][256]
    const float* __restrict__ Wout, const float* __restrict__ bout,
    float* __restrict__ out) {

  __shared__ _Float16 As[BM * 128];
  __shared__ _Float16 Bs[BN * 128];

  const int bid = blockIdx.x;
  const int nt = bid % 4;
  const int mt = bid / 4;
  const int t = threadIdx.x;
  const int lane = t & 63;
  const int wid = t >> 6;
  const int wr = wid >> 1, wc = wid & 1;
  const int mb = mt * BM;
  const int nb = nt * BN;

  f32x4 acc[2][2];
#pragma unroll
  for (int a = 0; a < 2; ++a)
#pragma unroll
    for (int b = 0; b < 2; ++b) acc[a][b] = (f32x4)0.f;

  for (int kc = 0; kc < 2; ++kc) {
    const int koff = kc * 128;
#pragma unroll
    for (int i = 0; i < 4; ++i) {
      const int g   = i * 256 + t;
      const int row = g >> 4;
      const int c8  = g & 15;
      const int eo  = row * 128 + (c8 ^ (row & 7)) * 8;

      int ar = mb + row; if (ar > M_TOTAL - 1) ar = M_TOTAL - 1;
      *reinterpret_cast<uint4*>(&As[eo]) =
          *reinterpret_cast<const uint4*>(sampH + (size_t)ar * 256 + koff + c8 * 8);

      const float4 w0 = *reinterpret_cast<const float4*>(Wout + (size_t)(nb + row) * KDIM + koff + c8 * 8);
      const float4 w1 = *reinterpret_cast<const float4*>(Wout + (size_t)(nb + row) * KDIM + koff + c8 * 8 + 4);
      union { _Float16 h[8]; uint4 u; } pb;
      pb.h[0] = (_Float16)w0.x; pb.h[1] = (_Float16)w0.y;
      pb.h[2] = (_Float16)w0.z; pb.h[3] = (_Float16)w0.w;
      pb.h[4] = (_Float16)w1.x; pb.h[5] = (_Float16)w1.y;
      pb.h[6] = (_Float16)w1.z; pb.h[7] = (_Float16)w1.w;
      *reinterpret_cast<uint4*>(&Bs[eo]) = pb.u;
    }
    __syncthreads();

#pragma unroll
    for (int kk = 0; kk < 4; ++kk) {
      f16x8 af[2], bf[2];
#pragma unroll
      for (int f = 0; f < 2; ++f) {
        const int arow = wr * 32 + f * 16 + (lane & 15);
        const int ac   = (kk * 4 + (lane >> 4)) ^ (arow & 7);
        af[f] = *reinterpret_cast<f16x8*>(&As[arow * 128 + ac * 8]);
        const int brow = wc * 32 + f * 16 + (lane & 15);
        const int bc   = (kk * 4 + (lane >> 4)) ^ (brow & 7);
        bf[f] = *reinterpret_cast<f16x8*>(&Bs[brow * 128 + bc * 8]);
      }
#pragma unroll
      for (int fr = 0; fr < 2; ++fr)
#pragma unroll
        for (int fc = 0; fc < 2; ++fc)
          acc[fr][fc] = __builtin_amdgcn_mfma_f32_16x16x32_f16(af[fr], bf[fc], acc[fr][fc], 0, 0, 0);
    }
    __syncthreads();
  }

  {
    const int col = lane & 15;
    const int rg4 = lane >> 4;
    float bias2[2];
    bias2[0] = bout[nb + wc * 32 + 0 * 16 + col];
    bias2[1] = bout[nb + wc * 32 + 1 * 16 + col];
#pragma unroll
    for (int fr = 0; fr < 2; ++fr) {
#pragma unroll
      for (int fc = 0; fc < 2; ++fc) {
        const int n = nb + wc * 32 + fc * 16 + col;
#pragma unroll
        for (int j = 0; j < 4; ++j) {
          const int m = mb + wr * 32 + fr * 16 + rg4 * 4 + j;
          if (m < M_TOTAL) {
            out[(size_t)m * EMB + n] = acc[fr][fc][j] + bias2[fc] + Q[(size_t)m * EMB + n];
          }
        }
      }
    }
  }
}

extern "C" void kernel_launch(void* const* d_in, const int* in_sizes, int n_in,
                              void* d_out, int out_size, void* d_ws, size_t ws_size,
                              hipStream_t stream) {
  const float* Q     = (const float*)d_in[0];
  const float* refp  = (const float*)d_in[1];
  const float* Wv    = (const float*)d_in[3];
  const float* bv    = (const float*)d_in[4];
  const float* Woff  = (const float*)d_in[5];
  const float* boff  = (const float*)d_in[6];
  const float* Wattn = (const float*)d_in[7];
  const float* battn = (const float*)d_in[8];
  const float* Wout  = (const float*)d_in[9];
  const float* bout  = (const float*)d_in[10];
  float* out = (float*)d_out;

  if (ws_size < WS_NEED2) return;   // proven to fit (round 9 main path ran)

  unsigned short* valH  = (unsigned short*)((char*)d_ws + WS_VAL_OFF);
  unsigned short* offH  = (unsigned short*)((char*)d_ws + WS_OFFW_OFF);
  unsigned short* attH  = (unsigned short*)((char*)d_ws + WS_ATT_OFF);
  unsigned short* sampH = (unsigned short*)((char*)d_ws + WS_SAMP_OFF);
  _Float16*       WH    = (_Float16*)((char*)d_ws + WS_WH_OFF);   // overlays sampH

  const int nblk_q8 = (M_TOTAL + QB - 1) / QB;   // 4456

  k_prep<<<dim3(80), dim3(256), 0, stream>>>(Wv, Woff, Wattn, WH);
  k_gemm1<<<dim3(MTILES), dim3(256), 0, stream>>>(Q, WH, bv, boff, battn,
                                                  valH, offH, attH);
  k_gather<<<dim3(nblk_q8), dim3(256), 0, stream>>>(refp, valH, offH, attH, sampH);
  k_gemm2<<<dim3(MTILES * 4), dim3(256), 0, stream>>>(Q, sampH, Wout, bout, out);
}

// Round 11
// 188.758 us; speedup vs baseline: 1.2420x; 1.2420x over previous
//
#include <hip/hip_runtime.h>
#include <math.h>

#define M_TOTAL 35642          // bs * nq
#define NQ_ 17821
#define NV_ 17821
#define EMB 256
#define KDIM 256
#define QB 8
#define BM 64
#define BN 64
#define NTILES 10              // 640 / 64
#define MTILES ((M_TOTAL + BM - 1) / BM)   // 557

// ---- workspace layout (bytes) ----
#define WS_VAL_OFF   0ull
#define WS_VAL_BYTES (2ull * M_TOTAL * EMB)        // f16 value, head-major [2][8][NV_][32]
#define WS_OFFW_OFF  (WS_VAL_OFF + WS_VAL_BYTES)
#define WS_OFFW_BYTES (2ull * M_TOTAL * EMB)       // f16 off  [m][256]
#define WS_ATT_OFF   (WS_OFFW_OFF + WS_OFFW_BYTES)
#define WS_ATT_BYTES (2ull * M_TOTAL * 128)        // f16 attn logits [m][128]
#define WS_SAMP_OFF  (WS_ATT_OFF + WS_ATT_BYTES)   // 45,621,760
#define WS_SAMP_BYTES (2ull * M_TOTAL * EMB)       // f16 samp [m][256]
#define WS_NEED2     (WS_SAMP_OFF + WS_SAMP_BYTES) // 63,870,464 B (proven fits)
// WH (f16 [640][256], 327,680 B) OVERLAYS the samp region (disjoint lifetimes).
#define WS_WH_OFF    WS_SAMP_OFF

using f16x8 = __attribute__((ext_vector_type(8))) _Float16;
using f32x4 = __attribute__((ext_vector_type(4))) float;

__device__ __forceinline__ unsigned short f2h(float f) {
  union { _Float16 h; unsigned short u; } v; v.h = (_Float16)f; return v.u;
}

// ---- k_prep: weights f32 -> f16 [640][256] ----
__global__ __launch_bounds__(256) void k_prep(
    const float* __restrict__ Wv, const float* __restrict__ Woff,
    const float* __restrict__ Wattn, _Float16* __restrict__ WH) {
  const int i = blockIdx.x * 256 + threadIdx.x;   // 8 elems each
  if (i >= 640 * 256 / 8) return;
  const int e   = i * 8;
  const int row = e >> 8;
  const int col = e & 255;
  const float* src = (row < 256) ? (Wv + (size_t)row * 256)
                   : (row < 512) ? (Woff + (size_t)(row - 256) * 256)
                                 : (Wattn + (size_t)(row - 512) * 256);
  const float4 a = *reinterpret_cast<const float4*>(src + col);
  const float4 b = *reinterpret_cast<const float4*>(src + col + 4);
  union { _Float16 h[8]; uint4 u; } p;
  p.h[0] = (_Float16)a.x; p.h[1] = (_Float16)a.y; p.h[2] = (_Float16)a.z; p.h[3] = (_Float16)a.w;
  p.h[4] = (_Float16)b.x; p.h[5] = (_Float16)b.y; p.h[6] = (_Float16)b.z; p.h[7] = (_Float16)b.w;
  *reinterpret_cast<uint4*>(WH + e) = p.u;
}

// ---- k_gemm1: one M-tile per block, loops all 10 N-tiles; A staged once ----
__global__ __launch_bounds__(256) void k_gemm1(
    const float* __restrict__ Q,
    const _Float16* __restrict__ WH,
    const float* __restrict__ bv, const float* __restrict__ boff,
    const float* __restrict__ battn,
    unsigned short* __restrict__ valH,
    unsigned short* __restrict__ offH,
    unsigned short* __restrict__ attH) {

  __shared__ _Float16 Sh[BM * 256];   // 32 KB, A then reused for each B tile

  const int t = threadIdx.x;
  const int lane = t & 63;
  const int wid = t >> 6;
  const int wr = wid >> 1, wc = wid & 1;
  const int mb = blockIdx.x * BM;

  // ---- stage A (Q rows, f32->f16, 16B-chunk XOR swizzle) ----
#pragma unroll
  for (int i = 0; i < 16; ++i) {
    const int g    = i * 256 + t;
    const int row  = g >> 6;
    const int c4   = g & 63;
    const int c8   = c4 >> 1;
    const int half = c4 & 1;
    const int eo   = row * 256 + ((c8 ^ (row & 7)) * 8) + half * 4;
    int ar = mb + row; if (ar > M_TOTAL - 1) ar = M_TOTAL - 1;
    const float4 qa = *reinterpret_cast<const float4*>(Q + (size_t)ar * KDIM + c4 * 4);
    union { _Float16 h[4]; uint2 u; } p;
    p.h[0] = (_Float16)qa.x; p.h[1] = (_Float16)qa.y;
    p.h[2] = (_Float16)qa.z; p.h[3] = (_Float16)qa.w;
    *reinterpret_cast<uint2*>(&Sh[eo]) = p.u;
  }
  __syncthreads();

  // ---- A-frags (full K) to registers: 16 x f16x8 = 64 VGPR ----
  f16x8 af[8][2];
#pragma unroll
  for (int kk = 0; kk < 8; ++kk)
#pragma unroll
    for (int f = 0; f < 2; ++f) {
      const int arow = wr * 32 + f * 16 + (lane & 15);
      const int ac   = (kk * 4 + (lane >> 4)) ^ (arow & 7);
      af[kk][f] = *reinterpret_cast<f16x8*>(&Sh[arow * 256 + ac * 8]);
    }
  __syncthreads();

  for (int nt = 0; nt < NTILES; ++nt) {
    const int nb = nt * BN;
#pragma unroll
    for (int i = 0; i < 8; ++i) {
      const int g   = i * 256 + t;
      const int row = g >> 5;
      const int c8  = g & 31;
      const int eo  = row * 256 + ((c8 ^ (row & 7)) * 8);
      *reinterpret_cast<uint4*>(&Sh[eo]) =
          *reinterpret_cast<const uint4*>(WH + (size_t)(nb + row) * 256 + c8 * 8);
    }
    __syncthreads();

    f32x4 acc[2][2];
#pragma unroll
    for (int a = 0; a < 2; ++a)
#pragma unroll
      for (int b = 0; b < 2; ++b) acc[a][b] = (f32x4)0.f;

#pragma unroll
    for (int kk = 0; kk < 8; ++kk) {
      f16x8 bf[2];
#pragma unroll
      for (int f = 0; f < 2; ++f) {
        const int brow = wc * 32 + f * 16 + (lane & 15);
        const int bc   = (kk * 4 + (lane >> 4)) ^ (brow & 7);
        bf[f] = *reinterpret_cast<f16x8*>(&Sh[brow * 256 + bc * 8]);
      }
#pragma unroll
      for (int fr = 0; fr < 2; ++fr)
#pragma unroll
        for (int fc = 0; fc < 2; ++fc)
          acc[fr][fc] = __builtin_amdgcn_mfma_f32_16x16x32_f16(af[kk][fr], bf[fc], acc[fr][fc], 0, 0, 0);
    }
    __syncthreads();

    {
      const float* bsec; int nsb;
      if (nt < 4)      { bsec = bv;    nsb = 0;   }
      else if (nt < 8) { bsec = boff;  nsb = 256; }
      else             { bsec = battn; nsb = 512; }
      const int nrow0 = nb - nsb;
      const int col = lane & 15;
      const int rg4 = lane >> 4;
      float bias2[2];
      bias2[0] = bsec[nrow0 + wc * 32 + 0 * 16 + col];
      bias2[1] = bsec[nrow0 + wc * 32 + 1 * 16 + col];
#pragma unroll
      for (int fr = 0; fr < 2; ++fr) {
#pragma unroll
        for (int fc = 0; fc < 2; ++fc) {
          const int n = nb + wc * 32 + fc * 16 + col;
#pragma unroll
          for (int j = 0; j < 4; ++j) {
            const int m = mb + wr * 32 + fr * 16 + rg4 * 4 + j;
            if (m < M_TOTAL) {
              const unsigned short o = f2h(acc[fr][fc][j] + bias2[fc]);
              if (nsb == 0) {
                const int b  = (m >= NQ_) ? 1 : 0;
                const int mm = m - b * NQ_;
                valH[((size_t)(b * 8 + (n >> 5)) * NV_ + mm) * 32 + (n & 31)] = o;
              } else if (nsb == 256) {
                offH[(size_t)m * 256 + (n - 256)] = o;
              } else {
                attH[(size_t)m * 128 + (n - 512)] = o;
              }
            }
          }
        }
      }
    }
  }
}

// ---- k_gather: softmax + bilinear gather -> f16 samp ws ----
// Round-9 scalar unpack+FMA accumulation (VGPR ~120, occupancy ~20%) +
// round-10's division-free coordinate math. NO perm/dot2 packing: that
// variant hit 188 VGPR and halved occupancy (r10 post-mortem).
__global__ __launch_bounds__(256) void k_gather(
    const float* __restrict__ refp,
    const unsigned short* __restrict__ valH,
    const unsigned short* __restrict__ offH,
    const unsigned short* __restrict__ attH,
    unsigned short* __restrict__ sampH) {

  const int t  = threadIdx.x;
  const int q0 = blockIdx.x * QB;
  const int q  = t >> 5;
  const int h  = (t >> 2) & 7;
  const int dq = t & 3;
  const int m  = q0 + q;
  const int mc = min(m, M_TOTAL - 1);

  // softmax over f16 logits
  float aw[16];
  {
    const f16x8 a0 = *reinterpret_cast<const f16x8*>(attH + (size_t)mc * 128 + h * 16);
    const f16x8 a1 = *reinterpret_cast<const f16x8*>(attH + (size_t)mc * 128 + h * 16 + 8);
#pragma unroll
    for (int i = 0; i < 8; ++i) { aw[i] = (float)a0[i]; aw[8 + i] = (float)a1[i]; }
  }
  float mx = aw[0];
#pragma unroll
  for (int i = 1; i < 16; ++i) mx = fmaxf(mx, aw[i]);
  float ssum = 0.f;
#pragma unroll
  for (int i = 0; i < 16; ++i) { aw[i] = __expf(aw[i] - mx); ssum += aw[i]; }
  const float inv = 1.0f / ssum;
#pragma unroll
  for (int i = 0; i < 16; ++i) aw[i] *= inv;

  float sacc[8];
#pragma unroll
  for (int d = 0; d < 8; ++d) sacc[d] = 0.f;

  {
    constexpr int LH[4] = {100, 50, 25, 13};
    constexpr int LW[4] = {134, 67, 34, 17};
    constexpr int LS[4] = {0, 13400, 16750, 17600};
    const int b = (mc >= NQ_) ? 1 : 0;
    const float* rp = refp + (size_t)mc * 8;
    const f16x8* vb = reinterpret_cast<const f16x8*>(valH) + (size_t)(b * 8 + h) * NV_ * 4 + dq;

#pragma unroll
    for (int lvl = 0; lvl < 4; ++lvl) {
      const int Hl = LH[lvl], Wl = LW[lvl], st = LS[lvl];
      const float Hf = (float)Hl, Wf = (float)Wl;
      const float2 rxy = *reinterpret_cast<const float2*>(rp + lvl * 2);
      const f16x8 ov = *reinterpret_cast<const f16x8*>(offH + (size_t)mc * 256 + h * 32 + lvl * 8);
#pragma unroll
      for (int p = 0; p < 4; ++p) {
        const float ox = (float)ov[p * 2 + 0];
        const float oy = (float)ov[p * 2 + 1];
        // (rx + ox/W)*W - 0.5 == rx*W + ox - 0.5 up to ~1 ulp (r10-verified)
        const float x = fmaf(rxy.x, Wf, ox) - 0.5f;
        const float y = fmaf(rxy.y, Hf, oy) - 0.5f;
        const float xf = floorf(x), yf = floorf(y);
        const float wx = x - xf, wy = y - yf;
        const int x0i = (int)xf, y0i = (int)yf;
        const int x1i = x0i + 1, y1i = y0i + 1;
        const float vx0 = (x0i >= 0 && x0i < Wl) ? 1.f : 0.f;
        const float vx1 = (x1i >= 0 && x1i < Wl) ? 1.f : 0.f;
        const float vy0 = (y0i >= 0 && y0i < Hl) ? 1.f : 0.f;
        const float vy1 = (y1i >= 0 && y1i < Hl) ? 1.f : 0.f;
        const int x0c = min(max(x0i, 0), Wl - 1);
        const int x1c = min(max(x1i, 0), Wl - 1);
        const int y0c = min(max(y0i, 0), Hl - 1);
        const int y1c = min(max(y1i, 0), Hl - 1);
        const float a = aw[lvl * 4 + p];
        const float w00 = a * (1.f - wy) * (1.f - wx) * (vy0 * vx0);
        const float w01 = a * (1.f - wy) * wx         * (vy0 * vx1);
        const float w10 = a * wy         * (1.f - wx) * (vy1 * vx0);
        const float w11 = a * wy         * wx         * (vy1 * vx1);
        const f16x8 v00 = vb[(size_t)(st + y0c * Wl + x0c) * 4];
        const f16x8 v01 = vb[(size_t)(st + y0c * Wl + x1c) * 4];
        const f16x8 v10 = vb[(size_t)(st + y1c * Wl + x0c) * 4];
        const f16x8 v11 = vb[(size_t)(st + y1c * Wl + x1c) * 4];
#pragma unroll
        for (int d = 0; d < 8; ++d) {
          sacc[d] += w00 * (float)v00[d] + w01 * (float)v01[d]
                   + w10 * (float)v10[d] + w11 * (float)v11[d];
        }
      }
    }
  }

  if (m < M_TOTAL) {
    union { _Float16 h[8]; uint4 u; } pk;
#pragma unroll
    for (int d = 0; d < 8; ++d) pk.h[d] = (_Float16)sacc[d];
    *reinterpret_cast<uint4*>(sampH + (size_t)m * 256 + h * 32 + dq * 8) = pk.u;
  }
}

// ---- k_gemm2: out = samp @ Wout^T + bout + Q (residual), MFMA ----
__global__ __launch_bounds__(256) void k_gemm2(
    const float* __restrict__ Q,
    const unsigned short* __restrict__ sampH,   // f16 bits [m][256]
    const float* __restrict__ Wout, const float* __restrict__ bout,
    float* __restrict__ out) {

  __shared__ _Float16 As[BM * 128];
  __shared__ _Float16 Bs[BN * 128];

  const int bid = blockIdx.x;
  const int nt = bid % 4;
  const int mt = bid / 4;
  const int t = threadIdx.x;
  const int lane = t & 63;
  const int wid = t >> 6;
  const int wr = wid >> 1, wc = wid & 1;
  const int mb = mt * BM;
  const int nb = nt * BN;

  f32x4 acc[2][2];
#pragma unroll
  for (int a = 0; a < 2; ++a)
#pragma unroll
    for (int b = 0; b < 2; ++b) acc[a][b] = (f32x4)0.f;

  for (int kc = 0; kc < 2; ++kc) {
    const int koff = kc * 128;
#pragma unroll
    for (int i = 0; i < 4; ++i) {
      const int g   = i * 256 + t;
      const int row = g >> 4;
      const int c8  = g & 15;
      const int eo  = row * 128 + (c8 ^ (row & 7)) * 8;

      int ar = mb + row; if (ar > M_TOTAL - 1) ar = M_TOTAL - 1;
      *reinterpret_cast<uint4*>(&As[eo]) =
          *reinterpret_cast<const uint4*>(sampH + (size_t)ar * 256 + koff + c8 * 8);

      const float4 w0 = *reinterpret_cast<const float4*>(Wout + (size_t)(nb + row) * KDIM + koff + c8 * 8);
      const float4 w1 = *reinterpret_cast<const float4*>(Wout + (size_t)(nb + row) * KDIM + koff + c8 * 8 + 4);
      union { _Float16 h[8]; uint4 u; } pb;
      pb.h[0] = (_Float16)w0.x; pb.h[1] = (_Float16)w0.y;
      pb.h[2] = (_Float16)w0.z; pb.h[3] = (_Float16)w0.w;
      pb.h[4] = (_Float16)w1.x; pb.h[5] = (_Float16)w1.y;
      pb.h[6] = (_Float16)w1.z; pb.h[7] = (_Float16)w1.w;
      *reinterpret_cast<uint4*>(&Bs[eo]) = pb.u;
    }
    __syncthreads();

#pragma unroll
    for (int kk = 0; kk < 4; ++kk) {
      f16x8 af[2], bf[2];
#pragma unroll
      for (int f = 0; f < 2; ++f) {
        const int arow = wr * 32 + f * 16 + (lane & 15);
        const int ac   = (kk * 4 + (lane >> 4)) ^ (arow & 7);
        af[f] = *reinterpret_cast<f16x8*>(&As[arow * 128 + ac * 8]);
        const int brow = wc * 32 + f * 16 + (lane & 15);
        const int bc   = (kk * 4 + (lane >> 4)) ^ (brow & 7);
        bf[f] = *reinterpret_cast<f16x8*>(&Bs[brow * 128 + bc * 8]);
      }
#pragma unroll
      for (int fr = 0; fr < 2; ++fr)
#pragma unroll
        for (int fc = 0; fc < 2; ++fc)
          acc[fr][fc] = __builtin_amdgcn_mfma_f32_16x16x32_f16(af[fr], bf[fc], acc[fr][fc], 0, 0, 0);
    }
    __syncthreads();
  }

  {
    const int col = lane & 15;
    const int rg4 = lane >> 4;
    float bias2[2];
    bias2[0] = bout[nb + wc * 32 + 0 * 16 + col];
    bias2[1] = bout[nb + wc * 32 + 1 * 16 + col];
#pragma unroll
    for (int fr = 0; fr < 2; ++fr) {
#pragma unroll
      for (int fc = 0; fc < 2; ++fc) {
        const int n = nb + wc * 32 + fc * 16 + col;
#pragma unroll
        for (int j = 0; j < 4; ++j) {
          const int m = mb + wr * 32 + fr * 16 + rg4 * 4 + j;
          if (m < M_TOTAL) {
            out[(size_t)m * EMB + n] = acc[fr][fc][j] + bias2[fc] + Q[(size_t)m * EMB + n];
          }
        }
      }
    }
  }
}

extern "C" void kernel_launch(void* const* d_in, const int* in_sizes, int n_in,
                              void* d_out, int out_size, void* d_ws, size_t ws_size,
                              hipStream_t stream) {
  const float* Q     = (const float*)d_in[0];
  const float* refp  = (const float*)d_in[1];
  const float* Wv    = (const float*)d_in[3];
  const float* bv    = (const float*)d_in[4];
  const float* Woff  = (const float*)d_in[5];
  const float* boff  = (const float*)d_in[6];
  const float* Wattn = (const float*)d_in[7];
  const float* battn = (const float*)d_in[8];
  const float* Wout  = (const float*)d_in[9];
  const float* bout  = (const float*)d_in[10];
  float* out = (float*)d_out;

  if (ws_size < WS_NEED2) return;

  unsigned short* valH  = (unsigned short*)((char*)d_ws + WS_VAL_OFF);
  unsigned short* offH  = (unsigned short*)((char*)d_ws + WS_OFFW_OFF);
  unsigned short* attH  = (unsigned short*)((char*)d_ws + WS_ATT_OFF);
  unsigned short* sampH = (unsigned short*)((char*)d_ws + WS_SAMP_OFF);
  _Float16*       WH    = (_Float16*)((char*)d_ws + WS_WH_OFF);   // overlays sampH

  const int nblk_q8 = (M_TOTAL + QB - 1) / QB;   // 4456

  k_prep<<<dim3(80), dim3(256), 0, stream>>>(Wv, Woff, Wattn, WH);
  k_gemm1<<<dim3(MTILES), dim3(256), 0, stream>>>(Q, WH, bv, boff, battn,
                                                  valH, offH, attH);
  k_gather<<<dim3(nblk_q8), dim3(256), 0, stream>>>(refp, valH, offH, attH, sampH);
  k_gemm2<<<dim3(MTILES * 4), dim3(256), 0, stream>>>(Q, sampH, Wout, bout, out);
}

// Round 12
// 169.875 us; speedup vs baseline: 1.3800x; 1.1112x over previous
//
#include <hip/hip_runtime.h>
#include <math.h>

#define M_TOTAL 35642          // bs * nq
#define NQ_ 17821
#define NV_ 17821
#define EMB 256
#define KDIM 256
#define QB 8
#define BM 64
#define BN 64
#define NTILES 10              // 640 / 64
#define MTILES ((M_TOTAL + BM - 1) / BM)   // 557

// ---- workspace layout (bytes) ----
#define WS_VAL_OFF   0ull
#define WS_VAL_BYTES (2ull * M_TOTAL * EMB)        // f16 value, head-major [2][8][NV_][32]
#define WS_OFFW_OFF  (WS_VAL_OFF + WS_VAL_BYTES)
#define WS_OFFW_BYTES (2ull * M_TOTAL * EMB)       // f16 off  [m][256]
#define WS_ATT_OFF   (WS_OFFW_OFF + WS_OFFW_BYTES)
#define WS_ATT_BYTES (2ull * M_TOTAL * 128)        // f16 attn logits [m][128]
#define WS_SAMP_OFF  (WS_ATT_OFF + WS_ATT_BYTES)   // 45,621,760
#define WS_SAMP_BYTES (2ull * M_TOTAL * EMB)       // f16 samp [m][256]
#define WS_NEED2     (WS_SAMP_OFF + WS_SAMP_BYTES) // 63,870,464 B (proven fits)
// WH (f16 [640][256], 327,680 B) OVERLAYS the samp region (disjoint lifetimes).
#define WS_WH_OFF    WS_SAMP_OFF

using f16x8 = __attribute__((ext_vector_type(8))) _Float16;
using f32x4 = __attribute__((ext_vector_type(4))) float;
typedef _Float16 h2 __attribute__((ext_vector_type(2)));

__device__ __forceinline__ unsigned short f2h(float f) {
  union { _Float16 h; unsigned short u; } v; v.h = (_Float16)f; return v.u;
}

// ---- k_prep: weights f32 -> f16 [640][256] ----
__global__ __launch_bounds__(256) void k_prep(
    const float* __restrict__ Wv, const float* __restrict__ Woff,
    const float* __restrict__ Wattn, _Float16* __restrict__ WH) {
  const int i = blockIdx.x * 256 + threadIdx.x;   // 8 elems each
  if (i >= 640 * 256 / 8) return;
  const int e   = i * 8;
  const int row = e >> 8;
  const int col = e & 255;
  const float* src = (row < 256) ? (Wv + (size_t)row * 256)
                   : (row < 512) ? (Woff + (size_t)(row - 256) * 256)
                                 : (Wattn + (size_t)(row - 512) * 256);
  const float4 a = *reinterpret_cast<const float4*>(src + col);
  const float4 b = *reinterpret_cast<const float4*>(src + col + 4);
  union { _Float16 h[8]; uint4 u; } p;
  p.h[0] = (_Float16)a.x; p.h[1] = (_Float16)a.y; p.h[2] = (_Float16)a.z; p.h[3] = (_Float16)a.w;
  p.h[4] = (_Float16)b.x; p.h[5] = (_Float16)b.y; p.h[6] = (_Float16)b.z; p.h[7] = (_Float16)b.w;
  *reinterpret_cast<uint4*>(WH + e) = p.u;
}

// ---- k_gemm1: grid = MTILES*2; each block does one M-tile x 5 N-tiles ----
// (r11 post-mortem: 557 blocks = 2.2/CU gave no inter-block overlap of
//  staging and MFMA; 1114 blocks = 4.3/CU, LDS 32KB allows 5.)
__global__ __launch_bounds__(256) void k_gemm1(
    const float* __restrict__ Q,
    const _Float16* __restrict__ WH,
    const float* __restrict__ bv, const float* __restrict__ boff,
    const float* __restrict__ battn,
    unsigned short* __restrict__ valH,
    unsigned short* __restrict__ offH,
    unsigned short* __restrict__ attH) {

  __shared__ _Float16 Sh[BM * 256];   // 32 KB, A then reused for each B tile

  const int t = threadIdx.x;
  const int lane = t & 63;
  const int wid = t >> 6;
  const int wr = wid >> 1, wc = wid & 1;
  const int mt = blockIdx.x >> 1;
  const int ng = blockIdx.x & 1;      // N-tile group: nt = ng*5 .. ng*5+4
  const int mb = mt * BM;

  // ---- stage A (Q rows, f32->f16, 16B-chunk XOR swizzle) ----
#pragma unroll
  for (int i = 0; i < 16; ++i) {
    const int g    = i * 256 + t;
    const int row  = g >> 6;
    const int c4   = g & 63;
    const int c8   = c4 >> 1;
    const int half = c4 & 1;
    const int eo   = row * 256 + ((c8 ^ (row & 7)) * 8) + half * 4;
    int ar = mb + row; if (ar > M_TOTAL - 1) ar = M_TOTAL - 1;
    const float4 qa = *reinterpret_cast<const float4*>(Q + (size_t)ar * KDIM + c4 * 4);
    union { _Float16 h[4]; uint2 u; } p;
    p.h[0] = (_Float16)qa.x; p.h[1] = (_Float16)qa.y;
    p.h[2] = (_Float16)qa.z; p.h[3] = (_Float16)qa.w;
    *reinterpret_cast<uint2*>(&Sh[eo]) = p.u;
  }
  __syncthreads();

  // ---- A-frags (full K) to registers: 16 x f16x8 = 64 VGPR ----
  f16x8 af[8][2];
#pragma unroll
  for (int kk = 0; kk < 8; ++kk)
#pragma unroll
    for (int f = 0; f < 2; ++f) {
      const int arow = wr * 32 + f * 16 + (lane & 15);
      const int ac   = (kk * 4 + (lane >> 4)) ^ (arow & 7);
      af[kk][f] = *reinterpret_cast<f16x8*>(&Sh[arow * 256 + ac * 8]);
    }
  __syncthreads();

  for (int nti = 0; nti < 5; ++nti) {
    const int nt = ng * 5 + nti;
    const int nb = nt * BN;
#pragma unroll
    for (int i = 0; i < 8; ++i) {
      const int g   = i * 256 + t;
      const int row = g >> 5;
      const int c8  = g & 31;
      const int eo  = row * 256 + ((c8 ^ (row & 7)) * 8);
      *reinterpret_cast<uint4*>(&Sh[eo]) =
          *reinterpret_cast<const uint4*>(WH + (size_t)(nb + row) * 256 + c8 * 8);
    }
    __syncthreads();

    f32x4 acc[2][2];
#pragma unroll
    for (int a = 0; a < 2; ++a)
#pragma unroll
      for (int b = 0; b < 2; ++b) acc[a][b] = (f32x4)0.f;

#pragma unroll
    for (int kk = 0; kk < 8; ++kk) {
      f16x8 bf[2];
#pragma unroll
      for (int f = 0; f < 2; ++f) {
        const int brow = wc * 32 + f * 16 + (lane & 15);
        const int bc   = (kk * 4 + (lane >> 4)) ^ (brow & 7);
        bf[f] = *reinterpret_cast<f16x8*>(&Sh[brow * 256 + bc * 8]);
      }
#pragma unroll
      for (int fr = 0; fr < 2; ++fr)
#pragma unroll
        for (int fc = 0; fc < 2; ++fc)
          acc[fr][fc] = __builtin_amdgcn_mfma_f32_16x16x32_f16(af[kk][fr], bf[fc], acc[fr][fc], 0, 0, 0);
    }
    __syncthreads();

    {
      const float* bsec; int nsb;
      if (nt < 4)      { bsec = bv;    nsb = 0;   }
      else if (nt < 8) { bsec = boff;  nsb = 256; }
      else             { bsec = battn; nsb = 512; }
      const int nrow0 = nb - nsb;
      const int col = lane & 15;
      const int rg4 = lane >> 4;
      float bias2[2];
      bias2[0] = bsec[nrow0 + wc * 32 + 0 * 16 + col];
      bias2[1] = bsec[nrow0 + wc * 32 + 1 * 16 + col];
#pragma unroll
      for (int fr = 0; fr < 2; ++fr) {
#pragma unroll
        for (int fc = 0; fc < 2; ++fc) {
          const int n = nb + wc * 32 + fc * 16 + col;
#pragma unroll
          for (int j = 0; j < 4; ++j) {
            const int m = mb + wr * 32 + fr * 16 + rg4 * 4 + j;
            if (m < M_TOTAL) {
              const unsigned short o = f2h(acc[fr][fc][j] + bias2[fc]);
              if (nsb == 0) {
                const int b  = (m >= NQ_) ? 1 : 0;
                const int mm = m - b * NQ_;
                valH[((size_t)(b * 8 + (n >> 5)) * NV_ + mm) * 32 + (n & 31)] = o;
              } else if (nsb == 256) {
                offH[(size_t)m * 256 + (n - 256)] = o;
              } else {
                attH[(size_t)m * 128 + (n - 512)] = o;
              }
            }
          }
        }
      }
    }
  }
}

// ---- k_gather: softmax + bilinear gather -> f16 samp ws ----
// Packed-f16 channel accumulation (v_pk_fma_f16): each corner's uint4 is
// bitcast in place to 4x h2 and consumed immediately (NO cross-corner
// repacking -> register-neutral, unlike the r10 perm/dot2 attempt).
__global__ __launch_bounds__(256) void k_gather(
    const float* __restrict__ refp,
    const unsigned short* __restrict__ valH,
    const unsigned short* __restrict__ offH,
    const unsigned short* __restrict__ attH,
    unsigned short* __restrict__ sampH) {

  const int t  = threadIdx.x;
  const int q0 = blockIdx.x * QB;
  const int q  = t >> 5;
  const int h  = (t >> 2) & 7;
  const int dq = t & 3;
  const int m  = q0 + q;
  const int mc = min(m, M_TOTAL - 1);

  // softmax over f16 logits
  float aw[16];
  {
    const f16x8 a0 = *reinterpret_cast<const f16x8*>(attH + (size_t)mc * 128 + h * 16);
    const f16x8 a1 = *reinterpret_cast<const f16x8*>(attH + (size_t)mc * 128 + h * 16 + 8);
#pragma unroll
    for (int i = 0; i < 8; ++i) { aw[i] = (float)a0[i]; aw[8 + i] = (float)a1[i]; }
  }
  float mx = aw[0];
#pragma unroll
  for (int i = 1; i < 16; ++i) mx = fmaxf(mx, aw[i]);
  float ssum = 0.f;
#pragma unroll
  for (int i = 0; i < 16; ++i) { aw[i] = __expf(aw[i] - mx); ssum += aw[i]; }
  const float inv = 1.0f / ssum;
#pragma unroll
  for (int i = 0; i < 16; ++i) aw[i] *= inv;

  h2 sacc2[4];
#pragma unroll
  for (int j = 0; j < 4; ++j) { sacc2[j][0] = (_Float16)0.f; sacc2[j][1] = (_Float16)0.f; }

  {
    constexpr int LH[4] = {100, 50, 25, 13};
    constexpr int LW[4] = {134, 67, 34, 17};
    constexpr int LS[4] = {0, 13400, 16750, 17600};
    const int b = (mc >= NQ_) ? 1 : 0;
    const float* rp = refp + (size_t)mc * 8;
    const uint4* vb = reinterpret_cast<const uint4*>(valH) + (size_t)(b * 8 + h) * NV_ * 4 + dq;

#pragma unroll
    for (int lvl = 0; lvl < 4; ++lvl) {
      const int Hl = LH[lvl], Wl = LW[lvl], st = LS[lvl];
      const float Hf = (float)Hl, Wf = (float)Wl;
      const float2 rxy = *reinterpret_cast<const float2*>(rp + lvl * 2);
      const f16x8 ov = *reinterpret_cast<const f16x8*>(offH + (size_t)mc * 256 + h * 32 + lvl * 8);
#pragma unroll
      for (int p = 0; p < 4; ++p) {
        const float ox = (float)ov[p * 2 + 0];
        const float oy = (float)ov[p * 2 + 1];
        // (rx + ox/W)*W - 0.5 == rx*W + ox - 0.5 up to ~1 ulp (r10-verified)
        const float x = fmaf(rxy.x, Wf, ox) - 0.5f;
        const float y = fmaf(rxy.y, Hf, oy) - 0.5f;
        const float xf = floorf(x), yf = floorf(y);
        const float wx = x - xf, wy = y - yf;
        const int x0i = (int)xf, y0i = (int)yf;
        const int x1i = x0i + 1, y1i = y0i + 1;
        const float vx0 = (x0i >= 0 && x0i < Wl) ? 1.f : 0.f;
        const float vx1 = (x1i >= 0 && x1i < Wl) ? 1.f : 0.f;
        const float vy0 = (y0i >= 0 && y0i < Hl) ? 1.f : 0.f;
        const float vy1 = (y1i >= 0 && y1i < Hl) ? 1.f : 0.f;
        const int x0c = min(max(x0i, 0), Wl - 1);
        const int x1c = min(max(x1i, 0), Wl - 1);
        const int y0c = min(max(y0i, 0), Hl - 1);
        const int y1c = min(max(y1i, 0), Hl - 1);
        const float a = aw[lvl * 4 + p];
        const float w00 = a * (1.f - wy) * (1.f - wx) * (vy0 * vx0);
        const float w01 = a * (1.f - wy) * wx         * (vy0 * vx1);
        const float w10 = a * wy         * (1.f - wx) * (vy1 * vx0);
        const float w11 = a * wy         * wx         * (vy1 * vx1);
        const _Float16 h00 = (_Float16)w00, h01 = (_Float16)w01;
        const _Float16 h10 = (_Float16)w10, h11 = (_Float16)w11;
        const h2 w00h = {h00, h00};
        const h2 w01h = {h01, h01};
        const h2 w10h = {h10, h10};
        const h2 w11h = {h11, h11};
        union UV { uint4 u; h2 hh[4]; };
        UV c00, c01, c10, c11;
        c00.u = vb[(size_t)(st + y0c * Wl + x0c) * 4];
        c01.u = vb[(size_t)(st + y0c * Wl + x1c) * 4];
        c10.u = vb[(size_t)(st + y1c * Wl + x0c) * 4];
        c11.u = vb[(size_t)(st + y1c * Wl + x1c) * 4];
#pragma unroll
        for (int j = 0; j < 4; ++j) {
          sacc2[j] += c00.hh[j] * w00h;
          sacc2[j] += c01.hh[j] * w01h;
          sacc2[j] += c10.hh[j] * w10h;
          sacc2[j] += c11.hh[j] * w11h;
        }
      }
    }
  }

  if (m < M_TOTAL) {
    union { h2 hh[4]; uint4 u; } pk;
#pragma unroll
    for (int j = 0; j < 4; ++j) pk.hh[j] = sacc2[j];
    *reinterpret_cast<uint4*>(sampH + (size_t)m * 256 + h * 32 + dq * 8) = pk.u;
  }
}

// ---- k_gemm2: out = samp @ Wout^T + bout + Q (residual), MFMA ----
__global__ __launch_bounds__(256) void k_gemm2(
    const float* __restrict__ Q,
    const unsigned short* __restrict__ sampH,   // f16 bits [m][256]
    const float* __restrict__ Wout, const float* __restrict__ bout,
    float* __restrict__ out) {

  __shared__ _Float16 As[BM * 128];
  __shared__ _Float16 Bs[BN * 128];

  const int bid = blockIdx.x;
  const int nt = bid % 4;
  const int mt = bid / 4;
  const int t = threadIdx.x;
  const int lane = t & 63;
  const int wid = t >> 6;
  const int wr = wid >> 1, wc = wid & 1;
  const int mb = mt * BM;
  const int nb = nt * BN;

  f32x4 acc[2][2];
#pragma unroll
  for (int a = 0; a < 2; ++a)
#pragma unroll
    for (int b = 0; b < 2; ++b) acc[a][b] = (f32x4)0.f;

  for (int kc = 0; kc < 2; ++kc) {
    const int koff = kc * 128;
#pragma unroll
    for (int i = 0; i < 4; ++i) {
      const int g   = i * 256 + t;
      const int row = g >> 4;
      const int c8  = g & 15;
      const int eo  = row * 128 + (c8 ^ (row & 7)) * 8;

      int ar = mb + row; if (ar > M_TOTAL - 1) ar = M_TOTAL - 1;
      *reinterpret_cast<uint4*>(&As[eo]) =
          *reinterpret_cast<const uint4*>(sampH + (size_t)ar * 256 + koff + c8 * 8);

      const float4 w0 = *reinterpret_cast<const float4*>(Wout + (size_t)(nb + row) * KDIM + koff + c8 * 8);
      const float4 w1 = *reinterpret_cast<const float4*>(Wout + (size_t)(nb + row) * KDIM + koff + c8 * 8 + 4);
      union { _Float16 h[8]; uint4 u; } pb;
      pb.h[0] = (_Float16)w0.x; pb.h[1] = (_Float16)w0.y;
      pb.h[2] = (_Float16)w0.z; pb.h[3] = (_Float16)w0.w;
      pb.h[4] = (_Float16)w1.x; pb.h[5] = (_Float16)w1.y;
      pb.h[6] = (_Float16)w1.z; pb.h[7] = (_Float16)w1.w;
      *reinterpret_cast<uint4*>(&Bs[eo]) = pb.u;
    }
    __syncthreads();

#pragma unroll
    for (int kk = 0; kk < 4; ++kk) {
      f16x8 af[2], bf[2];
#pragma unroll
      for (int f = 0; f < 2; ++f) {
        const int arow = wr * 32 + f * 16 + (lane & 15);
        const int ac   = (kk * 4 + (lane >> 4)) ^ (arow & 7);
        af[f] = *reinterpret_cast<f16x8*>(&As[arow * 128 + ac * 8]);
        const int brow = wc * 32 + f * 16 + (lane & 15);
        const int bc   = (kk * 4 + (lane >> 4)) ^ (brow & 7);
        bf[f] = *reinterpret_cast<f16x8*>(&Bs[brow * 128 + bc * 8]);
      }
#pragma unroll
      for (int fr = 0; fr < 2; ++fr)
#pragma unroll
        for (int fc = 0; fc < 2; ++fc)
          acc[fr][fc] = __builtin_amdgcn_mfma_f32_16x16x32_f16(af[fr], bf[fc], acc[fr][fc], 0, 0, 0);
    }
    __syncthreads();
  }

  {
    const int col = lane & 15;
    const int rg4 = lane >> 4;
    float bias2[2];
    bias2[0] = bout[nb + wc * 32 + 0 * 16 + col];
    bias2[1] = bout[nb + wc * 32 + 1 * 16 + col];
#pragma unroll
    for (int fr = 0; fr < 2; ++fr) {
#pragma unroll
      for (int fc = 0; fc < 2; ++fc) {
        const int n = nb + wc * 32 + fc * 16 + col;
#pragma unroll
        for (int j = 0; j < 4; ++j) {
          const int m = mb + wr * 32 + fr * 16 + rg4 * 4 + j;
          if (m < M_TOTAL) {
            out[(size_t)m * EMB + n] = acc[fr][fc][j] + bias2[fc] + Q[(size_t)m * EMB + n];
          }
        }
      }
    }
  }
}

extern "C" void kernel_launch(void* const* d_in, const int* in_sizes, int n_in,
                              void* d_out, int out_size, void* d_ws, size_t ws_size,
                              hipStream_t stream) {
  const float* Q     = (const float*)d_in[0];
  const float* refp  = (const float*)d_in[1];
  const float* Wv    = (const float*)d_in[3];
  const float* bv    = (const float*)d_in[4];
  const float* Woff  = (const float*)d_in[5];
  const float* boff  = (const float*)d_in[6];
  const float* Wattn = (const float*)d_in[7];
  const float* battn = (const float*)d_in[8];
  const float* Wout  = (const float*)d_in[9];
  const float* bout  = (const float*)d_in[10];
  float* out = (float*)d_out;

  if (ws_size < WS_NEED2) return;

  unsigned short* valH  = (unsigned short*)((char*)d_ws + WS_VAL_OFF);
  unsigned short* offH  = (unsigned short*)((char*)d_ws + WS_OFFW_OFF);
  unsigned short* attH  = (unsigned short*)((char*)d_ws + WS_ATT_OFF);
  unsigned short* sampH = (unsigned short*)((char*)d_ws + WS_SAMP_OFF);
  _Float16*       WH    = (_Float16*)((char*)d_ws + WS_WH_OFF);   // overlays sampH

  const int nblk_q8 = (M_TOTAL + QB - 1) / QB;   // 4456

  k_prep<<<dim3(80), dim3(256), 0, stream>>>(Wv, Woff, Wattn, WH);
  k_gemm1<<<dim3(MTILES * 2), dim3(256), 0, stream>>>(Q, WH, bv, boff, battn,
                                                      valH, offH, attH);
  k_gather<<<dim3(nblk_q8), dim3(256), 0, stream>>>(refp, valH, offH, attH, sampH);
  k_gemm2<<<dim3(MTILES * 4), dim3(256), 0, stream>>>(Q, sampH, Wout, bout, out);
}

// Round 13
// 160.011 us; speedup vs baseline: 1.4651x; 1.0616x over previous
//
#include <hip/hip_runtime.h>
#include <math.h>

#define M_TOTAL 35642          // bs * nq
#define NQ_ 17821
#define NV_ 17821
#define EMB 256
#define KDIM 256
#define QB 8
#define BM 64
#define BN 64
#define NTILES 10              // 640 / 64
#define MTILES ((M_TOTAL + BM - 1) / BM)   // 557

// ---- workspace layout (bytes) ----
#define WS_VAL_OFF   0ull
#define WS_VAL_BYTES (2ull * M_TOTAL * EMB)        // f16 value, head-major [2][8][NV_][32]
#define WS_OFFW_OFF  (WS_VAL_OFF + WS_VAL_BYTES)
#define WS_OFFW_BYTES (2ull * M_TOTAL * EMB)       // f16 off  [m][256]
#define WS_ATT_OFF   (WS_OFFW_OFF + WS_OFFW_BYTES)
#define WS_ATT_BYTES (2ull * M_TOTAL * 128)        // f16 attn logits [m][128]
#define WS_SAMP_OFF  (WS_ATT_OFF + WS_ATT_BYTES)   // 45,621,760
#define WS_SAMP_BYTES (2ull * M_TOTAL * EMB)       // f16 samp [m][256]
#define WS_NEED2     (WS_SAMP_OFF + WS_SAMP_BYTES) // 63,870,464 B (proven fits)
// WH (f16 [640][256], 327,680 B) OVERLAYS the samp region (disjoint lifetimes).
#define WS_WH_OFF    WS_SAMP_OFF

using f16x8 = __attribute__((ext_vector_type(8))) _Float16;
using f32x4 = __attribute__((ext_vector_type(4))) float;
typedef _Float16 h2 __attribute__((ext_vector_type(2)));

__device__ __forceinline__ unsigned short f2h(float f) {
  union { _Float16 h; unsigned short u; } v; v.h = (_Float16)f; return v.u;
}

// Bijective XCD-aware block swizzle (m204 variant): original bids == k (mod 8)
// run on XCD k (round-robin dispatch); map them to a CONTIGUOUS work chunk so
// each XCD's L2 sees a contiguous slice of the problem.
template <int NWG>
__device__ __forceinline__ int xcd_swz(int bid) {
  constexpr int q8 = NWG >> 3;
  constexpr int r8 = NWG & 7;
  const int xcd = bid & 7, idx = bid >> 3;
  return (xcd < r8 ? xcd * (q8 + 1) : r8 * (q8 + 1) + (xcd - r8) * q8) + idx;
}

// ---- k_prep: weights f32 -> f16 [640][256] ----
__global__ __launch_bounds__(256) void k_prep(
    const float* __restrict__ Wv, const float* __restrict__ Woff,
    const float* __restrict__ Wattn, _Float16* __restrict__ WH) {
  const int i = blockIdx.x * 256 + threadIdx.x;   // 8 elems each
  if (i >= 640 * 256 / 8) return;
  const int e   = i * 8;
  const int row = e >> 8;
  const int col = e & 255;
  const float* src = (row < 256) ? (Wv + (size_t)row * 256)
                   : (row < 512) ? (Woff + (size_t)(row - 256) * 256)
                                 : (Wattn + (size_t)(row - 512) * 256);
  const float4 a = *reinterpret_cast<const float4*>(src + col);
  const float4 b = *reinterpret_cast<const float4*>(src + col + 4);
  union { _Float16 h[8]; uint4 u; } p;
  p.h[0] = (_Float16)a.x; p.h[1] = (_Float16)a.y; p.h[2] = (_Float16)a.z; p.h[3] = (_Float16)a.w;
  p.h[4] = (_Float16)b.x; p.h[5] = (_Float16)b.y; p.h[6] = (_Float16)b.z; p.h[7] = (_Float16)b.w;
  *reinterpret_cast<uint4*>(WH + e) = p.u;
}

// ---- k_gemm1: grid = MTILES*2; each block: one M-tile x 5 N-tiles ----
__global__ __launch_bounds__(256) void k_gemm1(
    const float* __restrict__ Q,
    const _Float16* __restrict__ WH,
    const float* __restrict__ bv, const float* __restrict__ boff,
    const float* __restrict__ battn,
    unsigned short* __restrict__ valH,
    unsigned short* __restrict__ offH,
    unsigned short* __restrict__ attH) {

  __shared__ _Float16 Sh[BM * 256];   // 32 KB, A then reused for each B tile

  const int t = threadIdx.x;
  const int lane = t & 63;
  const int wid = t >> 6;
  const int wr = wid >> 1, wc = wid & 1;
  const int swz = xcd_swz<MTILES * 2>(blockIdx.x);   // pairs (mt,ng) share Q rows -> same XCD
  const int mt = swz >> 1;
  const int ng = swz & 1;             // N-tile group: nt = ng*5 .. ng*5+4
  const int mb = mt * BM;

  // ---- stage A (Q rows, f32->f16, 16B-chunk XOR swizzle) ----
#pragma unroll
  for (int i = 0; i < 16; ++i) {
    const int g    = i * 256 + t;
    const int row  = g >> 6;
    const int c4   = g & 63;
    const int c8   = c4 >> 1;
    const int half = c4 & 1;
    const int eo   = row * 256 + ((c8 ^ (row & 7)) * 8) + half * 4;
    int ar = mb + row; if (ar > M_TOTAL - 1) ar = M_TOTAL - 1;
    const float4 qa = *reinterpret_cast<const float4*>(Q + (size_t)ar * KDIM + c4 * 4);
    union { _Float16 h[4]; uint2 u; } p;
    p.h[0] = (_Float16)qa.x; p.h[1] = (_Float16)qa.y;
    p.h[2] = (_Float16)qa.z; p.h[3] = (_Float16)qa.w;
    *reinterpret_cast<uint2*>(&Sh[eo]) = p.u;
  }
  __syncthreads();

  // ---- A-frags (full K) to registers: 16 x f16x8 = 64 VGPR ----
  f16x8 af[8][2];
#pragma unroll
  for (int kk = 0; kk < 8; ++kk)
#pragma unroll
    for (int f = 0; f < 2; ++f) {
      const int arow = wr * 32 + f * 16 + (lane & 15);
      const int ac   = (kk * 4 + (lane >> 4)) ^ (arow & 7);
      af[kk][f] = *reinterpret_cast<f16x8*>(&Sh[arow * 256 + ac * 8]);
    }
  __syncthreads();

  for (int nti = 0; nti < 5; ++nti) {
    const int nt = ng * 5 + nti;
    const int nb = nt * BN;
#pragma unroll
    for (int i = 0; i < 8; ++i) {
      const int g   = i * 256 + t;
      const int row = g >> 5;
      const int c8  = g & 31;
      const int eo  = row * 256 + ((c8 ^ (row & 7)) * 8);
      *reinterpret_cast<uint4*>(&Sh[eo]) =
          *reinterpret_cast<const uint4*>(WH + (size_t)(nb + row) * 256 + c8 * 8);
    }
    __syncthreads();

    f32x4 acc[2][2];
#pragma unroll
    for (int a = 0; a < 2; ++a)
#pragma unroll
      for (int b = 0; b < 2; ++b) acc[a][b] = (f32x4)0.f;

#pragma unroll
    for (int kk = 0; kk < 8; ++kk) {
      f16x8 bf[2];
#pragma unroll
      for (int f = 0; f < 2; ++f) {
        const int brow = wc * 32 + f * 16 + (lane & 15);
        const int bc   = (kk * 4 + (lane >> 4)) ^ (brow & 7);
        bf[f] = *reinterpret_cast<f16x8*>(&Sh[brow * 256 + bc * 8]);
      }
#pragma unroll
      for (int fr = 0; fr < 2; ++fr)
#pragma unroll
        for (int fc = 0; fc < 2; ++fc)
          acc[fr][fc] = __builtin_amdgcn_mfma_f32_16x16x32_f16(af[kk][fr], bf[fc], acc[fr][fc], 0, 0, 0);
    }
    __syncthreads();

    {
      const float* bsec; int nsb;
      if (nt < 4)      { bsec = bv;    nsb = 0;   }
      else if (nt < 8) { bsec = boff;  nsb = 256; }
      else             { bsec = battn; nsb = 512; }
      const int nrow0 = nb - nsb;
      const int col = lane & 15;
      const int rg4 = lane >> 4;
      float bias2[2];
      bias2[0] = bsec[nrow0 + wc * 32 + 0 * 16 + col];
      bias2[1] = bsec[nrow0 + wc * 32 + 1 * 16 + col];
#pragma unroll
      for (int fr = 0; fr < 2; ++fr) {
#pragma unroll
        for (int fc = 0; fc < 2; ++fc) {
          const int n = nb + wc * 32 + fc * 16 + col;
#pragma unroll
          for (int j = 0; j < 4; ++j) {
            const int m = mb + wr * 32 + fr * 16 + rg4 * 4 + j;
            if (m < M_TOTAL) {
              const unsigned short o = f2h(acc[fr][fc][j] + bias2[fc]);
              if (nsb == 0) {
                const int b  = (m >= NQ_) ? 1 : 0;
                const int mm = m - b * NQ_;
                valH[((size_t)(b * 8 + (n >> 5)) * NV_ + mm) * 32 + (n & 31)] = o;
              } else if (nsb == 256) {
                offH[(size_t)m * 256 + (n - 256)] = o;
              } else {
                attH[(size_t)m * 128 + (n - 512)] = o;
              }
            }
          }
        }
      }
    }
  }
}

// ---- k_gather: softmax + bilinear gather -> f16 samp ws ----
// Packed-f16 accumulation (r12, VGPR 40) + XCD-contiguous block chunks so each
// XCD's L2 holds a ~2.3MB band of value instead of all 18.2MB (r12 FETCH
// showed ~7x value overfetch from round-robin dispatch).
__global__ __launch_bounds__(256) void k_gather(
    const float* __restrict__ refp,
    const unsigned short* __restrict__ valH,
    const unsigned short* __restrict__ offH,
    const unsigned short* __restrict__ attH,
    unsigned short* __restrict__ sampH) {

  const int t  = threadIdx.x;
  const int q0 = xcd_swz<(M_TOTAL + QB - 1) / QB>(blockIdx.x) * QB;
  const int q  = t >> 5;
  const int h  = (t >> 2) & 7;
  const int dq = t & 3;
  const int m  = q0 + q;
  const int mc = min(m, M_TOTAL - 1);

  // softmax over f16 logits
  float aw[16];
  {
    const f16x8 a0 = *reinterpret_cast<const f16x8*>(attH + (size_t)mc * 128 + h * 16);
    const f16x8 a1 = *reinterpret_cast<const f16x8*>(attH + (size_t)mc * 128 + h * 16 + 8);
#pragma unroll
    for (int i = 0; i < 8; ++i) { aw[i] = (float)a0[i]; aw[8 + i] = (float)a1[i]; }
  }
  float mx = aw[0];
#pragma unroll
  for (int i = 1; i < 16; ++i) mx = fmaxf(mx, aw[i]);
  float ssum = 0.f;
#pragma unroll
  for (int i = 0; i < 16; ++i) { aw[i] = __expf(aw[i] - mx); ssum += aw[i]; }
  const float inv = 1.0f / ssum;
#pragma unroll
  for (int i = 0; i < 16; ++i) aw[i] *= inv;

  h2 sacc2[4];
#pragma unroll
  for (int j = 0; j < 4; ++j) { sacc2[j][0] = (_Float16)0.f; sacc2[j][1] = (_Float16)0.f; }

  {
    constexpr int LH[4] = {100, 50, 25, 13};
    constexpr int LW[4] = {134, 67, 34, 17};
    constexpr int LS[4] = {0, 13400, 16750, 17600};
    const int b = (mc >= NQ_) ? 1 : 0;
    const float* rp = refp + (size_t)mc * 8;
    const uint4* vb = reinterpret_cast<const uint4*>(valH) + (size_t)(b * 8 + h) * NV_ * 4 + dq;

#pragma unroll
    for (int lvl = 0; lvl < 4; ++lvl) {
      const int Hl = LH[lvl], Wl = LW[lvl], st = LS[lvl];
      const float Hf = (float)Hl, Wf = (float)Wl;
      const float2 rxy = *reinterpret_cast<const float2*>(rp + lvl * 2);
      const f16x8 ov = *reinterpret_cast<const f16x8*>(offH + (size_t)mc * 256 + h * 32 + lvl * 8);
#pragma unroll
      for (int p = 0; p < 4; ++p) {
        const float ox = (float)ov[p * 2 + 0];
        const float oy = (float)ov[p * 2 + 1];
        // (rx + ox/W)*W - 0.5 == rx*W + ox - 0.5 up to ~1 ulp (r10-verified)
        const float x = fmaf(rxy.x, Wf, ox) - 0.5f;
        const float y = fmaf(rxy.y, Hf, oy) - 0.5f;
        const float xf = floorf(x), yf = floorf(y);
        const float wx = x - xf, wy = y - yf;
        const int x0i = (int)xf, y0i = (int)yf;
        const int x1i = x0i + 1, y1i = y0i + 1;
        const float vx0 = (x0i >= 0 && x0i < Wl) ? 1.f : 0.f;
        const float vx1 = (x1i >= 0 && x1i < Wl) ? 1.f : 0.f;
        const float vy0 = (y0i >= 0 && y0i < Hl) ? 1.f : 0.f;
        const float vy1 = (y1i >= 0 && y1i < Hl) ? 1.f : 0.f;
        const int x0c = min(max(x0i, 0), Wl - 1);
        const int x1c = min(max(x1i, 0), Wl - 1);
        const int y0c = min(max(y0i, 0), Hl - 1);
        const int y1c = min(max(y1i, 0), Hl - 1);
        const float a = aw[lvl * 4 + p];
        const float w00 = a * (1.f - wy) * (1.f - wx) * (vy0 * vx0);
        const float w01 = a * (1.f - wy) * wx         * (vy0 * vx1);
        const float w10 = a * wy         * (1.f - wx) * (vy1 * vx0);
        const float w11 = a * wy         * wx         * (vy1 * vx1);
        const _Float16 h00 = (_Float16)w00, h01 = (_Float16)w01;
        const _Float16 h10 = (_Float16)w10, h11 = (_Float16)w11;
        const h2 w00h = {h00, h00};
        const h2 w01h = {h01, h01};
        const h2 w10h = {h10, h10};
        const h2 w11h = {h11, h11};
        union UV { uint4 u; h2 hh[4]; };
        UV c00, c01, c10, c11;
        c00.u = vb[(size_t)(st + y0c * Wl + x0c) * 4];
        c01.u = vb[(size_t)(st + y0c * Wl + x1c) * 4];
        c10.u = vb[(size_t)(st + y1c * Wl + x0c) * 4];
        c11.u = vb[(size_t)(st + y1c * Wl + x1c) * 4];
#pragma unroll
        for (int j = 0; j < 4; ++j) {
          sacc2[j] += c00.hh[j] * w00h;
          sacc2[j] += c01.hh[j] * w01h;
          sacc2[j] += c10.hh[j] * w10h;
          sacc2[j] += c11.hh[j] * w11h;
        }
      }
    }
  }

  if (m < M_TOTAL) {
    union { h2 hh[4]; uint4 u; } pk;
#pragma unroll
    for (int j = 0; j < 4; ++j) pk.hh[j] = sacc2[j];
    *reinterpret_cast<uint4*>(sampH + (size_t)m * 256 + h * 32 + dq * 8) = pk.u;
  }
}

// ---- k_gemm2: out = samp @ Wout^T + bout + Q (residual), MFMA ----
__global__ __launch_bounds__(256) void k_gemm2(
    const float* __restrict__ Q,
    const unsigned short* __restrict__ sampH,   // f16 bits [m][256]
    const float* __restrict__ Wout, const float* __restrict__ bout,
    float* __restrict__ out) {

  __shared__ _Float16 As[BM * 128];
  __shared__ _Float16 Bs[BN * 128];

  const int swz = xcd_swz<MTILES * 4>(blockIdx.x);  // 4 same-A blocks -> same XCD
  const int nt = swz & 3;
  const int mt = swz >> 2;
  const int t = threadIdx.x;
  const int lane = t & 63;
  const int wid = t >> 6;
  const int wr = wid >> 1, wc = wid & 1;
  const int mb = mt * BM;
  const int nb = nt * BN;

  f32x4 acc[2][2];
#pragma unroll
  for (int a = 0; a < 2; ++a)
#pragma unroll
    for (int b = 0; b < 2; ++b) acc[a][b] = (f32x4)0.f;

  for (int kc = 0; kc < 2; ++kc) {
    const int koff = kc * 128;
#pragma unroll
    for (int i = 0; i < 4; ++i) {
      const int g   = i * 256 + t;
      const int row = g >> 4;
      const int c8  = g & 15;
      const int eo  = row * 128 + (c8 ^ (row & 7)) * 8;

      int ar = mb + row; if (ar > M_TOTAL - 1) ar = M_TOTAL - 1;
      *reinterpret_cast<uint4*>(&As[eo]) =
          *reinterpret_cast<const uint4*>(sampH + (size_t)ar * 256 + koff + c8 * 8);

      const float4 w0 = *reinterpret_cast<const float4*>(Wout + (size_t)(nb + row) * KDIM + koff + c8 * 8);
      const float4 w1 = *reinterpret_cast<const float4*>(Wout + (size_t)(nb + row) * KDIM + koff + c8 * 8 + 4);
      union { _Float16 h[8]; uint4 u; } pb;
      pb.h[0] = (_Float16)w0.x; pb.h[1] = (_Float16)w0.y;
      pb.h[2] = (_Float16)w0.z; pb.h[3] = (_Float16)w0.w;
      pb.h[4] = (_Float16)w1.x; pb.h[5] = (_Float16)w1.y;
      pb.h[6] = (_Float16)w1.z; pb.h[7] = (_Float16)w1.w;
      *reinterpret_cast<uint4*>(&Bs[eo]) = pb.u;
    }
    __syncthreads();

#pragma unroll
    for (int kk = 0; kk < 4; ++kk) {
      f16x8 af[2], bf[2];
#pragma unroll
      for (int f = 0; f < 2; ++f) {
        const int arow = wr * 32 + f * 16 + (lane & 15);
        const int ac   = (kk * 4 + (lane >> 4)) ^ (arow & 7);
        af[f] = *reinterpret_cast<f16x8*>(&As[arow * 128 + ac * 8]);
        const int brow = wc * 32 + f * 16 + (lane & 15);
        const int bc   = (kk * 4 + (lane >> 4)) ^ (brow & 7);
        bf[f] = *reinterpret_cast<f16x8*>(&Bs[brow * 128 + bc * 8]);
      }
#pragma unroll
      for (int fr = 0; fr < 2; ++fr)
#pragma unroll
        for (int fc = 0; fc < 2; ++fc)
          acc[fr][fc] = __builtin_amdgcn_mfma_f32_16x16x32_f16(af[fr], bf[fc], acc[fr][fc], 0, 0, 0);
    }
    __syncthreads();
  }

  {
    const int col = lane & 15;
    const int rg4 = lane >> 4;
    float bias2[2];
    bias2[0] = bout[nb + wc * 32 + 0 * 16 + col];
    bias2[1] = bout[nb + wc * 32 + 1 * 16 + col];
#pragma unroll
    for (int fr = 0; fr < 2; ++fr) {
#pragma unroll
      for (int fc = 0; fc < 2; ++fc) {
        const int n = nb + wc * 32 + fc * 16 + col;
#pragma unroll
        for (int j = 0; j < 4; ++j) {
          const int m = mb + wr * 32 + fr * 16 + rg4 * 4 + j;
          if (m < M_TOTAL) {
            out[(size_t)m * EMB + n] = acc[fr][fc][j] + bias2[fc] + Q[(size_t)m * EMB + n];
          }
        }
      }
    }
  }
}

extern "C" void kernel_launch(void* const* d_in, const int* in_sizes, int n_in,
                              void* d_out, int out_size, void* d_ws, size_t ws_size,
                              hipStream_t stream) {
  const float* Q     = (const float*)d_in[0];
  const float* refp  = (const float*)d_in[1];
  const float* Wv    = (const float*)d_in[3];
  const float* bv    = (const float*)d_in[4];
  const float* Woff  = (const float*)d_in[5];
  const float* boff  = (const float*)d_in[6];
  const float* Wattn = (const float*)d_in[7];
  const float* battn = (const float*)d_in[8];
  const float* Wout  = (const float*)d_in[9];
  const float* bout  = (const float*)d_in[10];
  float* out = (float*)d_out;

  if (ws_size < WS_NEED2) return;

  unsigned short* valH  = (unsigned short*)((char*)d_ws + WS_VAL_OFF);
  unsigned short* offH  = (unsigned short*)((char*)d_ws + WS_OFFW_OFF);
  unsigned short* attH  = (unsigned short*)((char*)d_ws + WS_ATT_OFF);
  unsigned short* sampH = (unsigned short*)((char*)d_ws + WS_SAMP_OFF);
  _Float16*       WH    = (_Float16*)((char*)d_ws + WS_WH_OFF);   // overlays sampH

  const int nblk_q8 = (M_TOTAL + QB - 1) / QB;   // 4456

  k_prep<<<dim3(80), dim3(256), 0, stream>>>(Wv, Woff, Wattn, WH);
  k_gemm1<<<dim3(MTILES * 2), dim3(256), 0, stream>>>(Q, WH, bv, boff, battn,
                                                      valH, offH, attH);
  k_gather<<<dim3(nblk_q8), dim3(256), 0, stream>>>(refp, valH, offH, attH, sampH);
  k_gemm2<<<dim3(MTILES * 4), dim3(256), 0, stream>>>(Q, sampH, Wout, bout, out);
}